// Round 10
// baseline (260.402 us; speedup 1.0000x reference)
//
#include <hip/hip_runtime.h>

// WassersteinLoss: per-row W1 = (1/N) * sum_i |sort(u)[i] - sort(v)[i]|, mean over rows.
// R14: spill fix + dual-ror m=4. R13 post-mortem: PASSED (builtin permlane +
//   min3 CE correct) but 157us > R8's 149: WRITE_SIZE 12.3MB = small spill from
//   32 in-flight uv2 permlane results (scheduler hoists the whole unrolled pass).
//   R13 also explains R10-R12: inline-asm swap with two "+v" operands fed the
//   SAME value got register-coalesced -> v_permlane16_swap v0,v0 = garbage.
//   The m=4 dual-ror (only in R10/R11) was never independently convicted.
//   Changes vs R13:
//   1) chunk permlane passes with sched_barrier(0) every 8 CEs -> bounded live
//      range, spill gone (tripwire: WRITE_SIZE ~64 KB).
//   2) m=4 (x4 passes) -> dual DPP ror (ror:12 = x[(l+4)%16] for keep-min
//      bit2=0 lanes; ror:4 = x[l-4] for keep-max; verified lane-by-lane vs the
//      documented row_shr scan idiom). 3 VALU, 0 DS per CE. -256 DS insts.
//   3) m=16/32 builtin permlane + min3 CE kept (R13-proven).
//   DS/thread ~706 (R8) -> ~260 (bperm mirrors X31/X63 + LDS stage only).
//   Pred: 135-145us kernel. Gate: absmax!=0 -> revert m=4 only.
// Carried: blocked layout, ascending mirror bitonic, 2-VALU ce2, DPP m=1,2,8 +
//   mirrors X=1,3,7,15, wave-role-split LDS t^127 stage (17 KB, 0 conflicts),
//   launch_bounds(256,4).

constexpr int N_ELEM  = 4096;
constexpr int V       = 32;     // elements per thread per array
constexpr int THREADS = 256;    // 4 waves = 2 rows per block

#if __has_builtin(__builtin_amdgcn_permlane16_swap) && __has_builtin(__builtin_amdgcn_permlane32_swap)
#define HAVE_PLSWAP 1
typedef unsigned uv2 __attribute__((ext_vector_type(2)));
#else
#define HAVE_PLSWAP 0
#endif

// ---- compare-select: keep min(x,o) if keep_min, else max(x,o). ----
__device__ __forceinline__ float ce2(float x, float o, bool keep_min) {
    return ((o < x) != keep_min) ? x : o;
}

// ---- in-register ascending merge of S-blocks: mirror + descend S/4..1 ----
template<int S>
__device__ __forceinline__ void reg_merge(float r[V]) {
    #pragma unroll
    for (int k = 0; k < V; ++k) {
        if ((k & (S >> 1)) == 0) {
            const int j = k ^ (S - 1);          // complement low bits = mirror partner
            const float a = r[k], b = r[j];
            r[k] = fminf(a, b);
            r[j] = fmaxf(a, b);
        }
    }
    #pragma unroll
    for (int s = S >> 2; s >= 1; s >>= 1) {
        #pragma unroll
        for (int k = 0; k < V; ++k) {
            if ((k & s) == 0) {
                const float a = r[k], b = r[k + s];
                r[k]     = fminf(a, b);
                r[k + s] = fmaxf(a, b);
            }
        }
    }
}

// ---- ascending register descend, strides 16..1 (tail of every cross stage) ----
__device__ __forceinline__ void reg_tail_asc(float r[V]) {
    #pragma unroll
    for (int s = 16; s >= 1; s >>= 1) {
        #pragma unroll
        for (int k = 0; k < V; ++k) {
            if ((k & s) == 0) {
                const float a = r[k], b = r[k + s];
                r[k]     = fminf(a, b);
                r[k + s] = fmaxf(a, b);
            }
        }
    }
}

template<int CTRL>
__device__ __forceinline__ float dpp_x(float x) {
    return __int_as_float(__builtin_amdgcn_mov_dpp(__float_as_int(x), CTRL, 0xF, 0xF, true));
}
__device__ __forceinline__ float bperm_x(int pa, float x) {
    return __int_as_float(__builtin_amdgcn_ds_bpermute(pa, __float_as_int(x)));
}

#if HAVE_PLSWAP
// Robust permlane CE: r = swap(x, x) -> {r0,r1} = {own, partner} per lane
// (order lane-dependent); min3/max3 including x is correct regardless.
__device__ __forceinline__ float pl16_ce(float x, bool keep_min) {
    const unsigned xu = __float_as_uint(x);
    const uv2 r = __builtin_amdgcn_permlane16_swap(xu, xu, false, false);
    const float a = __uint_as_float(r[0]);
    const float b = __uint_as_float(r[1]);
    return keep_min ? fminf(fminf(x, a), b) : fmaxf(fmaxf(x, a), b);
}
__device__ __forceinline__ float pl32_ce(float x, bool keep_min) {
    const unsigned xu = __float_as_uint(x);
    const uv2 r = __builtin_amdgcn_permlane32_swap(xu, xu, false, false);
    const float a = __uint_as_float(r[0]);
    const float b = __uint_as_float(r[1]);
    return keep_min ? fminf(fminf(x, a), b) : fmaxf(fmaxf(x, a), b);
}
#endif

// ---- descend xor pass, lane partner lane^M, keep_min at (lane&M)==0 ----
template<int M>
__device__ __forceinline__ void xor_pass(float ru[V], float rv[V], int lane) {
    const bool keep_min = (lane & M) == 0;
    if constexpr (M == 1 || M == 2 || M == 8) {
        constexpr int ctrl = (M == 1) ? 0xB1 : (M == 2) ? 0x4E : 0x128;
        #pragma unroll
        for (int k = 0; k < V; ++k) {
            ru[k] = ce2(ru[k], dpp_x<ctrl>(ru[k]), keep_min);
            rv[k] = ce2(rv[k], dpp_x<ctrl>(rv[k]), keep_min);
        }
    } else if constexpr (M == 4) {
        // Dual-ror: keep-min lanes (bit2=0) read partner l+4 via ror:12;
        // keep-max lanes read l-4 via ror:4. Single-use dpps fuse to
        // v_min_f32_dpp / v_max_f32_dpp; + v_cndmask = 3 VALU, 0 DS.
        #pragma unroll
        for (int k = 0; k < V; ++k) {
            const float uu = dpp_x<0x12C>(ru[k]);   // row_ror:12 -> x[(l+4)&15]
            const float ud = dpp_x<0x124>(ru[k]);   // row_ror:4  -> x[(l-4)&15]
            ru[k] = keep_min ? fminf(ru[k], uu) : fmaxf(ru[k], ud);
            const float vu = dpp_x<0x12C>(rv[k]);
            const float vd = dpp_x<0x124>(rv[k]);
            rv[k] = keep_min ? fminf(rv[k], vu) : fmaxf(rv[k], vd);
        }
    } else if constexpr (M == 16) {
#if HAVE_PLSWAP
        #pragma unroll
        for (int k = 0; k < V; ++k) {
            ru[k] = pl16_ce(ru[k], keep_min);
            rv[k] = pl16_ce(rv[k], keep_min);
            if ((k & 3) == 3) __builtin_amdgcn_sched_barrier(0);  // cap live range
        }
#else
        const int pa = (lane ^ 16) << 2;
        #pragma unroll
        for (int k = 0; k < V; ++k) {
            ru[k] = ce2(ru[k], bperm_x(pa, ru[k]), keep_min);
            rv[k] = ce2(rv[k], bperm_x(pa, rv[k]), keep_min);
        }
#endif
    } else {  // M == 32
#if HAVE_PLSWAP
        #pragma unroll
        for (int k = 0; k < V; ++k) {
            ru[k] = pl32_ce(ru[k], keep_min);
            rv[k] = pl32_ce(rv[k], keep_min);
            if ((k & 3) == 3) __builtin_amdgcn_sched_barrier(0);  // cap live range
        }
#else
        const int pa = (lane ^ 32) << 2;
        #pragma unroll
        for (int k = 0; k < V; ++k) {
            ru[k] = ce2(ru[k], bperm_x(pa, ru[k]), keep_min);
            rv[k] = ce2(rv[k], bperm_x(pa, rv[k]), keep_min);
        }
#endif
    }
}

// ---- cross descend m=MMAX..1 then register tail (strides 16..1) ----
template<int MMAX>
__device__ __forceinline__ void cross_descend(float ru[V], float rv[V], int lane) {
    if constexpr (MMAX >= 32) xor_pass<32>(ru, rv, lane);
    if constexpr (MMAX >= 16) xor_pass<16>(ru, rv, lane);
    if constexpr (MMAX >= 8)  xor_pass<8>(ru, rv, lane);
    if constexpr (MMAX >= 4)  xor_pass<4>(ru, rv, lane);
    if constexpr (MMAX >= 2)  xor_pass<2>(ru, rv, lane);
    if constexpr (MMAX >= 1)  xor_pass<1>(ru, rv, lane);
    reg_tail_asc(ru);
    reg_tail_asc(rv);
}

// DPP ctrl for mirror partner lane^X, or -1 (-> bperm).
template<int X>
static constexpr int mirror_dpp_ctrl() {
    return X == 1 ? 0xB1 : X == 3 ? 0x1B : X == 7 ? 0x141 : X == 15 ? 0x140 : -1;
}

// ---- cross mirror pass: (t,k) <-> (t^X, 31-k); keep_min at (t & (X+1)/2)==0.
//      Pairs (k, 31-k) handled jointly so reads precede writes (no hazard). ----
template<int X>
__device__ __forceinline__ void mirror_pass(float ru[V], float rv[V], int lane) {
    const bool keep_min = (lane & ((X + 1) >> 1)) == 0;
    constexpr int ctrl = mirror_dpp_ctrl<X>();
    if constexpr (ctrl != -1) {
        #pragma unroll
        for (int k = 0; k < V / 2; ++k) {
            const int j = V - 1 - k;
            const float ua = dpp_x<ctrl>(ru[j]);
            const float ub = dpp_x<ctrl>(ru[k]);
            ru[k] = ce2(ru[k], ua, keep_min);
            ru[j] = ce2(ru[j], ub, keep_min);
            const float va = dpp_x<ctrl>(rv[j]);
            const float vb = dpp_x<ctrl>(rv[k]);
            rv[k] = ce2(rv[k], va, keep_min);
            rv[j] = ce2(rv[j], vb, keep_min);
        }
    } else {
        const int pa = (lane ^ X) << 2;
        #pragma unroll
        for (int k = 0; k < V / 2; ++k) {
            const int j = V - 1 - k;
            const float ua = bperm_x(pa, ru[j]);
            const float ub = bperm_x(pa, ru[k]);
            ru[k] = ce2(ru[k], ua, keep_min);
            ru[j] = ce2(ru[j], ub, keep_min);
            const float va = bperm_x(pa, rv[j]);
            const float vb = bperm_x(pa, rv[k]);
            rv[k] = ce2(rv[k], va, keep_min);
            rv[j] = ce2(rv[j], vb, keep_min);
        }
    }
}

// ---- full merge stage S (64..2048): cross mirror + cross descend + reg tail ----
template<int S>
__device__ __forceinline__ void stage_m(float ru[V], float rv[V], int lane) {
    mirror_pass<(S >> 5) - 1>(ru, rv, lane);   // X = S/32 - 1  (t-bit mirror mask)
    cross_descend<(S >> 7)>(ru, rv, lane);     // descend strides S/4..32 -> m = S/128..1
}

__global__ __launch_bounds__(THREADS, 4) void w1_rows_kernel(
    const float* __restrict__ pred,
    const float* __restrict__ tru,
    float* __restrict__ out,
    float scale)
{
    // Staging for UPPER threads only (t&64): 128 slots x stride 33 = 16896 B.
    __shared__ float xbuf[128 * 33];
    __shared__ float wsum[THREADS / 64];

    const int tid  = threadIdx.x;
    const int t    = tid & 127;            // thread index within the row (0..127)
    const int lane = tid & 63;
    const int row  = blockIdx.x * 2 + (tid >> 7);
    const size_t base = (size_t)row * N_ELEM + (size_t)t * V;

    // Blocked layout: row-thread t owns global indices [32t, 32t+32).
    float ru[V], rv[V];
    {
        const float4* u4 = (const float4*)(pred + base);
        const float4* v4 = (const float4*)(tru  + base);
        #pragma unroll
        for (int c = 0; c < V / 4; ++c) {
            float4 a = u4[c], b = v4[c];
            ru[4*c+0] = a.x; ru[4*c+1] = a.y; ru[4*c+2] = a.z; ru[4*c+3] = a.w;
            rv[4*c+0] = b.x; rv[4*c+1] = b.y; rv[4*c+2] = b.z; rv[4*c+3] = b.w;
        }
    }

    // Stages S=2..32: fully in-register ascending sort of each 32-run.
    reg_merge<2>(ru);  reg_merge<2>(rv);
    reg_merge<4>(ru);  reg_merge<4>(rv);
    reg_merge<8>(ru);  reg_merge<8>(rv);
    reg_merge<16>(ru); reg_merge<16>(rv);
    reg_merge<32>(ru); reg_merge<32>(rv);

    // Stages S=64..2048: cross-lane mirror + descend, everything ascending.
    stage_m<64>(ru, rv, lane);
    stage_m<128>(ru, rv, lane);
    stage_m<256>(ru, rv, lane);
    stage_m<512>(ru, rv, lane);
    stage_m<1024>(ru, rv, lane);
    stage_m<2048>(ru, rv, lane);

    // Stage S=4096: mirror pass g <-> g^4095, i.e. (t,k) <-> (t^127, 31-k).
    // Wave-role split: uppers (t&64) stage all 32 regs; lowers read partner
    // reversed, keep min, write max back; uppers re-read. Wave-uniform branches.
    {
        const bool is_upper = (t & 64) != 0;
        const int  slot_row = (tid >> 7) * 64;
        const int  my_base  = (slot_row + lane) * 33;        // uppers' own slot
        const int  pa_base  = (slot_row + (63 - lane)) * 33; // lowers' partner slot

        // ---- array u ----
        if (is_upper) {
            #pragma unroll
            for (int k = 0; k < V; ++k) xbuf[my_base + k] = ru[k];
        }
        __syncthreads();
        if (!is_upper) {
            #pragma unroll
            for (int k = 0; k < V; ++k) {
                const int  e = V - 1 - k;
                const float o  = xbuf[pa_base + e];
                const float mx = fmaxf(ru[k], o);
                ru[k] = fminf(ru[k], o);          // lower keeps min
                xbuf[pa_base + e] = mx;           // partner's result
            }
        }
        __syncthreads();
        if (is_upper) {
            #pragma unroll
            for (int k = 0; k < V; ++k) ru[k] = xbuf[my_base + k];
        }

        // ---- array v ---- (uppers' own-slot read->write is program-ordered)
        if (is_upper) {
            #pragma unroll
            for (int k = 0; k < V; ++k) xbuf[my_base + k] = rv[k];
        }
        __syncthreads();
        if (!is_upper) {
            #pragma unroll
            for (int k = 0; k < V; ++k) {
                const int  e = V - 1 - k;
                const float o  = xbuf[pa_base + e];
                const float mx = fmaxf(rv[k], o);
                rv[k] = fminf(rv[k], o);
                xbuf[pa_base + e] = mx;
            }
        }
        __syncthreads();
        if (is_upper) {
            #pragma unroll
            for (int k = 0; k < V; ++k) rv[k] = xbuf[my_base + k];
        }

        cross_descend<32>(ru, rv, lane);       // strides 1024..32 then reg tail
    }

    // Epilogue: per-thread |diff| sum, wave reduce, block reduce, one atomic.
    float part = 0.f;
    #pragma unroll
    for (int k = 0; k < V; ++k) part += fabsf(ru[k] - rv[k]);

    #pragma unroll
    for (int off = 32; off > 0; off >>= 1)
        part += __shfl_down(part, off, 64);

    const int wid = tid >> 6;
    if (lane == 0) wsum[wid] = part;
    __syncthreads();
    if (tid == 0) {
        float tot = wsum[0] + wsum[1] + wsum[2] + wsum[3];
        atomicAdd(out, tot * scale);
    }
}

extern "C" void kernel_launch(void* const* d_in, const int* in_sizes, int n_in,
                              void* d_out, int out_size, void* d_ws, size_t ws_size,
                              hipStream_t stream)
{
    (void)n_in; (void)out_size; (void)d_ws; (void)ws_size;

    const float* pred = (const float*)d_in[0];
    const float* tru  = (const float*)d_in[1];
    float* out = (float*)d_out;

    const int B = in_sizes[0] / N_ELEM;   // 4096 rows

    hipMemsetAsync(out, 0, sizeof(float), stream);

    const float scale = 1.0f / ((float)N_ELEM * (float)B);
    w1_rows_kernel<<<B / 2, THREADS, 0, stream>>>(pred, tru, out, scale);
}

// Round 11
// 242.953 us; speedup vs baseline: 1.0718x; 1.0718x over previous
//
#include <hip/hip_runtime.h>

// WassersteinLoss: per-row W1 = (1/N) * sum_i |sort(u)[i] - sort(v)[i]|, mean over rows.
// R15: full revert to R8 exchanges + software-pipelined bperm passes.
//   R13/R14 post-mortem (the conversion law): permlane min3 CE = 5 VALU/elem
//   (divergent keep_min forces min3+max3+cndmask), dual-ror likewise 5 -> both
//   conversions trade 1 DS for +3 VALU and LOSE (R14 product 147us vs R8 116us).
//   Trading 1 DS for <=2 VALU wins (R8); >=3 loses. No <=2-VALU lane^16/32
//   exchange exists -> R8's bperm set is the local optimum. Permlane deleted
//   (also carried 10-12MB scratch).
//   New: the 7 xor-bperm passes (m=4 x4, m=16 x2, m=32 x1; 448 DS) restructured
//   as 16-elem issue/consume pipeline interleaved across u/v: 32 DS in flight
//   overlap 32 CE VALU within the wave -> attack R8's 33us non-VALU exposure.
//   Same ops, same per-array order -> bit-identical. Temps +16 regs (~90 live,
//   <128 cap). Mirrors X31/X63 + LDS stage byte-identical to R8.
//   Pred: 138-145us if compiler wasn't pipelining; >=148 -> R8 is the ceiling.
// Carried from R8: blocked layout, ascending mirror bitonic, 2-VALU ce2,
//   DPP m=1,2,8 + mirrors X=1,3,7,15, wave-role-split LDS t^127 stage
//   (17 KB, 0 conflicts), launch_bounds(256,4) (tripwire: WRITE_SIZE ~64 KB).

constexpr int N_ELEM  = 4096;
constexpr int V       = 32;     // elements per thread per array
constexpr int THREADS = 256;    // 4 waves = 2 rows per block

// ---- compare-select: keep min(x,o) if keep_min, else max(x,o). ----
__device__ __forceinline__ float ce2(float x, float o, bool keep_min) {
    return ((o < x) != keep_min) ? x : o;
}

// ---- in-register ascending merge of S-blocks: mirror + descend S/4..1 ----
template<int S>
__device__ __forceinline__ void reg_merge(float r[V]) {
    #pragma unroll
    for (int k = 0; k < V; ++k) {
        if ((k & (S >> 1)) == 0) {
            const int j = k ^ (S - 1);          // complement low bits = mirror partner
            const float a = r[k], b = r[j];
            r[k] = fminf(a, b);
            r[j] = fmaxf(a, b);
        }
    }
    #pragma unroll
    for (int s = S >> 2; s >= 1; s >>= 1) {
        #pragma unroll
        for (int k = 0; k < V; ++k) {
            if ((k & s) == 0) {
                const float a = r[k], b = r[k + s];
                r[k]     = fminf(a, b);
                r[k + s] = fmaxf(a, b);
            }
        }
    }
}

// ---- ascending register descend, strides 16..1 (tail of every cross stage) ----
__device__ __forceinline__ void reg_tail_asc(float r[V]) {
    #pragma unroll
    for (int s = 16; s >= 1; s >>= 1) {
        #pragma unroll
        for (int k = 0; k < V; ++k) {
            if ((k & s) == 0) {
                const float a = r[k], b = r[k + s];
                r[k]     = fminf(a, b);
                r[k + s] = fmaxf(a, b);
            }
        }
    }
}

template<int CTRL>
__device__ __forceinline__ float dpp_x(float x) {
    return __int_as_float(__builtin_amdgcn_mov_dpp(__float_as_int(x), CTRL, 0xF, 0xF, true));
}
__device__ __forceinline__ float bperm_x(int pa, float x) {
    return __int_as_float(__builtin_amdgcn_ds_bpermute(pa, __float_as_int(x)));
}

// ---- descend xor pass, lane partner lane^M, keep_min at (lane&M)==0 ----
//      DPP (m=1,2,8): ce2 per elem. bperm (m=4,16,32): 16-elem issue/consume
//      pipeline interleaved across u/v so DS latency overlaps CE VALU.
template<int M>
__device__ __forceinline__ void xor_pass(float ru[V], float rv[V], int lane) {
    const bool keep_min = (lane & M) == 0;
    if constexpr (M == 1 || M == 2 || M == 8) {
        constexpr int ctrl = (M == 1) ? 0xB1 : (M == 2) ? 0x4E : 0x128;
        #pragma unroll
        for (int k = 0; k < V; ++k) {
            ru[k] = ce2(ru[k], dpp_x<ctrl>(ru[k]), keep_min);
            rv[k] = ce2(rv[k], dpp_x<ctrl>(rv[k]), keep_min);
        }
    } else {
        const int pa = (lane ^ M) << 2;
        float tu[16], tv[16];
        #pragma unroll
        for (int k = 0; k < 16; ++k) tu[k] = bperm_x(pa, ru[k]);       // issue u0
        #pragma unroll
        for (int k = 0; k < 16; ++k) tv[k] = bperm_x(pa, rv[k]);       // issue v0
        #pragma unroll
        for (int k = 0; k < 16; ++k) ru[k] = ce2(ru[k], tu[k], keep_min);   // consume u0
        #pragma unroll
        for (int k = 0; k < 16; ++k) tu[k] = bperm_x(pa, ru[16 + k]);  // issue u1
        #pragma unroll
        for (int k = 0; k < 16; ++k) rv[k] = ce2(rv[k], tv[k], keep_min);   // consume v0
        #pragma unroll
        for (int k = 0; k < 16; ++k) tv[k] = bperm_x(pa, rv[16 + k]);  // issue v1
        #pragma unroll
        for (int k = 0; k < 16; ++k) ru[16 + k] = ce2(ru[16 + k], tu[k], keep_min);
        #pragma unroll
        for (int k = 0; k < 16; ++k) rv[16 + k] = ce2(rv[16 + k], tv[k], keep_min);
    }
}

// ---- cross descend m=MMAX..1 then register tail (strides 16..1) ----
template<int MMAX>
__device__ __forceinline__ void cross_descend(float ru[V], float rv[V], int lane) {
    if constexpr (MMAX >= 32) xor_pass<32>(ru, rv, lane);
    if constexpr (MMAX >= 16) xor_pass<16>(ru, rv, lane);
    if constexpr (MMAX >= 8)  xor_pass<8>(ru, rv, lane);
    if constexpr (MMAX >= 4)  xor_pass<4>(ru, rv, lane);
    if constexpr (MMAX >= 2)  xor_pass<2>(ru, rv, lane);
    if constexpr (MMAX >= 1)  xor_pass<1>(ru, rv, lane);
    reg_tail_asc(ru);
    reg_tail_asc(rv);
}

// DPP ctrl for mirror partner lane^X, or -1 (-> bperm).
template<int X>
static constexpr int mirror_dpp_ctrl() {
    return X == 1 ? 0xB1 : X == 3 ? 0x1B : X == 7 ? 0x141 : X == 15 ? 0x140 : -1;
}

// ---- cross mirror pass: (t,k) <-> (t^X, 31-k); keep_min at (t & (X+1)/2)==0.
//      Pairs (k, 31-k) handled jointly so reads precede writes (no hazard). ----
template<int X>
__device__ __forceinline__ void mirror_pass(float ru[V], float rv[V], int lane) {
    const bool keep_min = (lane & ((X + 1) >> 1)) == 0;
    constexpr int ctrl = mirror_dpp_ctrl<X>();
    if constexpr (ctrl != -1) {
        #pragma unroll
        for (int k = 0; k < V / 2; ++k) {
            const int j = V - 1 - k;
            const float ua = dpp_x<ctrl>(ru[j]);
            const float ub = dpp_x<ctrl>(ru[k]);
            ru[k] = ce2(ru[k], ua, keep_min);
            ru[j] = ce2(ru[j], ub, keep_min);
            const float va = dpp_x<ctrl>(rv[j]);
            const float vb = dpp_x<ctrl>(rv[k]);
            rv[k] = ce2(rv[k], va, keep_min);
            rv[j] = ce2(rv[j], vb, keep_min);
        }
    } else {
        const int pa = (lane ^ X) << 2;
        #pragma unroll
        for (int k = 0; k < V / 2; ++k) {
            const int j = V - 1 - k;
            const float ua = bperm_x(pa, ru[j]);
            const float ub = bperm_x(pa, ru[k]);
            ru[k] = ce2(ru[k], ua, keep_min);
            ru[j] = ce2(ru[j], ub, keep_min);
            const float va = bperm_x(pa, rv[j]);
            const float vb = bperm_x(pa, rv[k]);
            rv[k] = ce2(rv[k], va, keep_min);
            rv[j] = ce2(rv[j], vb, keep_min);
        }
    }
}

// ---- full merge stage S (64..2048): cross mirror + cross descend + reg tail ----
template<int S>
__device__ __forceinline__ void stage_m(float ru[V], float rv[V], int lane) {
    mirror_pass<(S >> 5) - 1>(ru, rv, lane);   // X = S/32 - 1  (t-bit mirror mask)
    cross_descend<(S >> 7)>(ru, rv, lane);     // descend strides S/4..32 -> m = S/128..1
}

__global__ __launch_bounds__(THREADS, 4) void w1_rows_kernel(
    const float* __restrict__ pred,
    const float* __restrict__ tru,
    float* __restrict__ out,
    float scale)
{
    // Staging for UPPER threads only (t&64): 128 slots x stride 33 = 16896 B.
    __shared__ float xbuf[128 * 33];
    __shared__ float wsum[THREADS / 64];

    const int tid  = threadIdx.x;
    const int t    = tid & 127;            // thread index within the row (0..127)
    const int lane = tid & 63;
    const int row  = blockIdx.x * 2 + (tid >> 7);
    const size_t base = (size_t)row * N_ELEM + (size_t)t * V;

    // Blocked layout: row-thread t owns global indices [32t, 32t+32).
    float ru[V], rv[V];
    {
        const float4* u4 = (const float4*)(pred + base);
        const float4* v4 = (const float4*)(tru  + base);
        #pragma unroll
        for (int c = 0; c < V / 4; ++c) {
            float4 a = u4[c], b = v4[c];
            ru[4*c+0] = a.x; ru[4*c+1] = a.y; ru[4*c+2] = a.z; ru[4*c+3] = a.w;
            rv[4*c+0] = b.x; rv[4*c+1] = b.y; rv[4*c+2] = b.z; rv[4*c+3] = b.w;
        }
    }

    // Stages S=2..32: fully in-register ascending sort of each 32-run.
    reg_merge<2>(ru);  reg_merge<2>(rv);
    reg_merge<4>(ru);  reg_merge<4>(rv);
    reg_merge<8>(ru);  reg_merge<8>(rv);
    reg_merge<16>(ru); reg_merge<16>(rv);
    reg_merge<32>(ru); reg_merge<32>(rv);

    // Stages S=64..2048: cross-lane mirror + descend, everything ascending.
    stage_m<64>(ru, rv, lane);
    stage_m<128>(ru, rv, lane);
    stage_m<256>(ru, rv, lane);
    stage_m<512>(ru, rv, lane);
    stage_m<1024>(ru, rv, lane);
    stage_m<2048>(ru, rv, lane);

    // Stage S=4096: mirror pass g <-> g^4095, i.e. (t,k) <-> (t^127, 31-k).
    // Wave-role split: uppers (t&64) stage all 32 regs; lowers read partner
    // reversed, keep min, write max back; uppers re-read. Wave-uniform branches.
    {
        const bool is_upper = (t & 64) != 0;
        const int  slot_row = (tid >> 7) * 64;
        const int  my_base  = (slot_row + lane) * 33;        // uppers' own slot
        const int  pa_base  = (slot_row + (63 - lane)) * 33; // lowers' partner slot

        // ---- array u ----
        if (is_upper) {
            #pragma unroll
            for (int k = 0; k < V; ++k) xbuf[my_base + k] = ru[k];
        }
        __syncthreads();
        if (!is_upper) {
            #pragma unroll
            for (int k = 0; k < V; ++k) {
                const int  e = V - 1 - k;
                const float o  = xbuf[pa_base + e];
                const float mx = fmaxf(ru[k], o);
                ru[k] = fminf(ru[k], o);          // lower keeps min
                xbuf[pa_base + e] = mx;           // partner's result
            }
        }
        __syncthreads();
        if (is_upper) {
            #pragma unroll
            for (int k = 0; k < V; ++k) ru[k] = xbuf[my_base + k];
        }

        // ---- array v ---- (uppers' own-slot read->write is program-ordered)
        if (is_upper) {
            #pragma unroll
            for (int k = 0; k < V; ++k) xbuf[my_base + k] = rv[k];
        }
        __syncthreads();
        if (!is_upper) {
            #pragma unroll
            for (int k = 0; k < V; ++k) {
                const int  e = V - 1 - k;
                const float o  = xbuf[pa_base + e];
                const float mx = fmaxf(rv[k], o);
                rv[k] = fminf(rv[k], o);
                xbuf[pa_base + e] = mx;
            }
        }
        __syncthreads();
        if (is_upper) {
            #pragma unroll
            for (int k = 0; k < V; ++k) rv[k] = xbuf[my_base + k];
        }

        cross_descend<32>(ru, rv, lane);       // strides 1024..32 then reg tail
    }

    // Epilogue: per-thread |diff| sum, wave reduce, block reduce, one atomic.
    float part = 0.f;
    #pragma unroll
    for (int k = 0; k < V; ++k) part += fabsf(ru[k] - rv[k]);

    #pragma unroll
    for (int off = 32; off > 0; off >>= 1)
        part += __shfl_down(part, off, 64);

    const int wid = tid >> 6;
    if (lane == 0) wsum[wid] = part;
    __syncthreads();
    if (tid == 0) {
        float tot = wsum[0] + wsum[1] + wsum[2] + wsum[3];
        atomicAdd(out, tot * scale);
    }
}

extern "C" void kernel_launch(void* const* d_in, const int* in_sizes, int n_in,
                              void* d_out, int out_size, void* d_ws, size_t ws_size,
                              hipStream_t stream)
{
    (void)n_in; (void)out_size; (void)d_ws; (void)ws_size;

    const float* pred = (const float*)d_in[0];
    const float* tru  = (const float*)d_in[1];
    float* out = (float*)d_out;

    const int B = in_sizes[0] / N_ELEM;   // 4096 rows

    hipMemsetAsync(out, 0, sizeof(float), stream);

    const float scale = 1.0f / ((float)N_ELEM * (float)B);
    w1_rows_kernel<<<B / 2, THREADS, 0, stream>>>(pred, tru, out, scale);
}

// Round 12
// 240.844 us; speedup vs baseline: 1.0812x; 1.0088x over previous
//
#include <hip/hip_runtime.h>

// WassersteinLoss: per-row W1 = (1/N) * sum_i |sort(u)[i] - sort(v)[i]|, mean over rows.
// R16: merged u/v LDS staging — 4 barriers -> 2 in the S=4096 stage.
//   R15 post-mortem: SW-pipelined bperm = neutral (~1us); compiler already
//   scheduled it. Law: dur ~= VALU stream (116us) + ~32us structural. Five
//   attacks on the structural term failed inside passes; the remaining cheap
//   piece is the S=4096 stage's 4 __syncthreads + 2 sequential LDS drains.
//   Change: double xbuf (2 x 128 x 33 = 33.8 KB), uppers stage u AND v, one
//   sync, lowers CE both (interleaved, 2x LDS ILP), one sync, uppers re-read.
//   Same DS ops, same per-array order -> bit-identical. Measured occupancy was
//   38% at BOTH 17KB and 34KB LDS (bounds=4 attribute caps 4 blocks/CU) -> no
//   occupancy cost. Pred: 142-146us; >=147 -> structural floor, declare ceiling.
// Carried from R8/R15: blocked layout, ascending mirror bitonic, 2-VALU ce2,
//   DPP m=1,2,8 + mirrors X=1,3,7,15, pipelined bperm m=4,16,32 + mirrors
//   X=31,63, launch_bounds(256,4) (tripwire: WRITE_SIZE ~64 KB).

constexpr int N_ELEM  = 4096;
constexpr int V       = 32;     // elements per thread per array
constexpr int THREADS = 256;    // 4 waves = 2 rows per block

// ---- compare-select: keep min(x,o) if keep_min, else max(x,o). ----
__device__ __forceinline__ float ce2(float x, float o, bool keep_min) {
    return ((o < x) != keep_min) ? x : o;
}

// ---- in-register ascending merge of S-blocks: mirror + descend S/4..1 ----
template<int S>
__device__ __forceinline__ void reg_merge(float r[V]) {
    #pragma unroll
    for (int k = 0; k < V; ++k) {
        if ((k & (S >> 1)) == 0) {
            const int j = k ^ (S - 1);          // complement low bits = mirror partner
            const float a = r[k], b = r[j];
            r[k] = fminf(a, b);
            r[j] = fmaxf(a, b);
        }
    }
    #pragma unroll
    for (int s = S >> 2; s >= 1; s >>= 1) {
        #pragma unroll
        for (int k = 0; k < V; ++k) {
            if ((k & s) == 0) {
                const float a = r[k], b = r[k + s];
                r[k]     = fminf(a, b);
                r[k + s] = fmaxf(a, b);
            }
        }
    }
}

// ---- ascending register descend, strides 16..1 (tail of every cross stage) ----
__device__ __forceinline__ void reg_tail_asc(float r[V]) {
    #pragma unroll
    for (int s = 16; s >= 1; s >>= 1) {
        #pragma unroll
        for (int k = 0; k < V; ++k) {
            if ((k & s) == 0) {
                const float a = r[k], b = r[k + s];
                r[k]     = fminf(a, b);
                r[k + s] = fmaxf(a, b);
            }
        }
    }
}

template<int CTRL>
__device__ __forceinline__ float dpp_x(float x) {
    return __int_as_float(__builtin_amdgcn_mov_dpp(__float_as_int(x), CTRL, 0xF, 0xF, true));
}
__device__ __forceinline__ float bperm_x(int pa, float x) {
    return __int_as_float(__builtin_amdgcn_ds_bpermute(pa, __float_as_int(x)));
}

// ---- descend xor pass, lane partner lane^M, keep_min at (lane&M)==0 ----
//      DPP (m=1,2,8): ce2 per elem. bperm (m=4,16,32): 16-elem issue/consume
//      pipeline interleaved across u/v so DS latency overlaps CE VALU.
template<int M>
__device__ __forceinline__ void xor_pass(float ru[V], float rv[V], int lane) {
    const bool keep_min = (lane & M) == 0;
    if constexpr (M == 1 || M == 2 || M == 8) {
        constexpr int ctrl = (M == 1) ? 0xB1 : (M == 2) ? 0x4E : 0x128;
        #pragma unroll
        for (int k = 0; k < V; ++k) {
            ru[k] = ce2(ru[k], dpp_x<ctrl>(ru[k]), keep_min);
            rv[k] = ce2(rv[k], dpp_x<ctrl>(rv[k]), keep_min);
        }
    } else {
        const int pa = (lane ^ M) << 2;
        float tu[16], tv[16];
        #pragma unroll
        for (int k = 0; k < 16; ++k) tu[k] = bperm_x(pa, ru[k]);       // issue u0
        #pragma unroll
        for (int k = 0; k < 16; ++k) tv[k] = bperm_x(pa, rv[k]);       // issue v0
        #pragma unroll
        for (int k = 0; k < 16; ++k) ru[k] = ce2(ru[k], tu[k], keep_min);   // consume u0
        #pragma unroll
        for (int k = 0; k < 16; ++k) tu[k] = bperm_x(pa, ru[16 + k]);  // issue u1
        #pragma unroll
        for (int k = 0; k < 16; ++k) rv[k] = ce2(rv[k], tv[k], keep_min);   // consume v0
        #pragma unroll
        for (int k = 0; k < 16; ++k) tv[k] = bperm_x(pa, rv[16 + k]);  // issue v1
        #pragma unroll
        for (int k = 0; k < 16; ++k) ru[16 + k] = ce2(ru[16 + k], tu[k], keep_min);
        #pragma unroll
        for (int k = 0; k < 16; ++k) rv[16 + k] = ce2(rv[16 + k], tv[k], keep_min);
    }
}

// ---- cross descend m=MMAX..1 then register tail (strides 16..1) ----
template<int MMAX>
__device__ __forceinline__ void cross_descend(float ru[V], float rv[V], int lane) {
    if constexpr (MMAX >= 32) xor_pass<32>(ru, rv, lane);
    if constexpr (MMAX >= 16) xor_pass<16>(ru, rv, lane);
    if constexpr (MMAX >= 8)  xor_pass<8>(ru, rv, lane);
    if constexpr (MMAX >= 4)  xor_pass<4>(ru, rv, lane);
    if constexpr (MMAX >= 2)  xor_pass<2>(ru, rv, lane);
    if constexpr (MMAX >= 1)  xor_pass<1>(ru, rv, lane);
    reg_tail_asc(ru);
    reg_tail_asc(rv);
}

// DPP ctrl for mirror partner lane^X, or -1 (-> bperm).
template<int X>
static constexpr int mirror_dpp_ctrl() {
    return X == 1 ? 0xB1 : X == 3 ? 0x1B : X == 7 ? 0x141 : X == 15 ? 0x140 : -1;
}

// ---- cross mirror pass: (t,k) <-> (t^X, 31-k); keep_min at (t & (X+1)/2)==0.
//      Pairs (k, 31-k) handled jointly so reads precede writes (no hazard). ----
template<int X>
__device__ __forceinline__ void mirror_pass(float ru[V], float rv[V], int lane) {
    const bool keep_min = (lane & ((X + 1) >> 1)) == 0;
    constexpr int ctrl = mirror_dpp_ctrl<X>();
    if constexpr (ctrl != -1) {
        #pragma unroll
        for (int k = 0; k < V / 2; ++k) {
            const int j = V - 1 - k;
            const float ua = dpp_x<ctrl>(ru[j]);
            const float ub = dpp_x<ctrl>(ru[k]);
            ru[k] = ce2(ru[k], ua, keep_min);
            ru[j] = ce2(ru[j], ub, keep_min);
            const float va = dpp_x<ctrl>(rv[j]);
            const float vb = dpp_x<ctrl>(rv[k]);
            rv[k] = ce2(rv[k], va, keep_min);
            rv[j] = ce2(rv[j], vb, keep_min);
        }
    } else {
        const int pa = (lane ^ X) << 2;
        #pragma unroll
        for (int k = 0; k < V / 2; ++k) {
            const int j = V - 1 - k;
            const float ua = bperm_x(pa, ru[j]);
            const float ub = bperm_x(pa, ru[k]);
            ru[k] = ce2(ru[k], ua, keep_min);
            ru[j] = ce2(ru[j], ub, keep_min);
            const float va = bperm_x(pa, rv[j]);
            const float vb = bperm_x(pa, rv[k]);
            rv[k] = ce2(rv[k], va, keep_min);
            rv[j] = ce2(rv[j], vb, keep_min);
        }
    }
}

// ---- full merge stage S (64..2048): cross mirror + cross descend + reg tail ----
template<int S>
__device__ __forceinline__ void stage_m(float ru[V], float rv[V], int lane) {
    mirror_pass<(S >> 5) - 1>(ru, rv, lane);   // X = S/32 - 1  (t-bit mirror mask)
    cross_descend<(S >> 7)>(ru, rv, lane);     // descend strides S/4..32 -> m = S/128..1
}

__global__ __launch_bounds__(THREADS, 4) void w1_rows_kernel(
    const float* __restrict__ pred,
    const float* __restrict__ tru,
    float* __restrict__ out,
    float scale)
{
    // Merged staging for UPPER threads (t&64): u-half [0, 4224), v-half
    // [4224, 8448) floats; 128 slots x stride 33 each = 33792 B total.
    __shared__ float xbuf[2 * 128 * 33];
    __shared__ float wsum[THREADS / 64];

    const int tid  = threadIdx.x;
    const int t    = tid & 127;            // thread index within the row (0..127)
    const int lane = tid & 63;
    const int row  = blockIdx.x * 2 + (tid >> 7);
    const size_t base = (size_t)row * N_ELEM + (size_t)t * V;

    // Blocked layout: row-thread t owns global indices [32t, 32t+32).
    float ru[V], rv[V];
    {
        const float4* u4 = (const float4*)(pred + base);
        const float4* v4 = (const float4*)(tru  + base);
        #pragma unroll
        for (int c = 0; c < V / 4; ++c) {
            float4 a = u4[c], b = v4[c];
            ru[4*c+0] = a.x; ru[4*c+1] = a.y; ru[4*c+2] = a.z; ru[4*c+3] = a.w;
            rv[4*c+0] = b.x; rv[4*c+1] = b.y; rv[4*c+2] = b.z; rv[4*c+3] = b.w;
        }
    }

    // Stages S=2..32: fully in-register ascending sort of each 32-run.
    reg_merge<2>(ru);  reg_merge<2>(rv);
    reg_merge<4>(ru);  reg_merge<4>(rv);
    reg_merge<8>(ru);  reg_merge<8>(rv);
    reg_merge<16>(ru); reg_merge<16>(rv);
    reg_merge<32>(ru); reg_merge<32>(rv);

    // Stages S=64..2048: cross-lane mirror + descend, everything ascending.
    stage_m<64>(ru, rv, lane);
    stage_m<128>(ru, rv, lane);
    stage_m<256>(ru, rv, lane);
    stage_m<512>(ru, rv, lane);
    stage_m<1024>(ru, rv, lane);
    stage_m<2048>(ru, rv, lane);

    // Stage S=4096: mirror pass g <-> g^4095, i.e. (t,k) <-> (t^127, 31-k).
    // Wave-role split, MERGED u/v staging: uppers (t&64) stage both arrays;
    // one sync; lowers CE both (read partner reversed, keep min, write max
    // back); one sync; uppers re-read both. Wave-uniform branches.
    {
        const bool is_upper = (t & 64) != 0;
        const int  slot_row = (tid >> 7) * 64;
        const int  my_u = (slot_row + lane) * 33;            // uppers' own slots
        const int  my_v = 4224 + my_u;
        const int  pa_u = (slot_row + (63 - lane)) * 33;     // lowers' partner slots
        const int  pa_v = 4224 + pa_u;

        if (is_upper) {
            #pragma unroll
            for (int k = 0; k < V; ++k) xbuf[my_u + k] = ru[k];
            #pragma unroll
            for (int k = 0; k < V; ++k) xbuf[my_v + k] = rv[k];
        }
        __syncthreads();
        if (!is_upper) {
            #pragma unroll
            for (int k = 0; k < V; ++k) {
                const int  e = V - 1 - k;
                const float ou = xbuf[pa_u + e];
                const float ov = xbuf[pa_v + e];
                const float mu = fmaxf(ru[k], ou);
                const float mv = fmaxf(rv[k], ov);
                ru[k] = fminf(ru[k], ou);         // lower keeps min
                rv[k] = fminf(rv[k], ov);
                xbuf[pa_u + e] = mu;              // partner's results
                xbuf[pa_v + e] = mv;
            }
        }
        __syncthreads();
        if (is_upper) {
            #pragma unroll
            for (int k = 0; k < V; ++k) ru[k] = xbuf[my_u + k];
            #pragma unroll
            for (int k = 0; k < V; ++k) rv[k] = xbuf[my_v + k];
        }

        cross_descend<32>(ru, rv, lane);       // strides 1024..32 then reg tail
    }

    // Epilogue: per-thread |diff| sum, wave reduce, block reduce, one atomic.
    float part = 0.f;
    #pragma unroll
    for (int k = 0; k < V; ++k) part += fabsf(ru[k] - rv[k]);

    #pragma unroll
    for (int off = 32; off > 0; off >>= 1)
        part += __shfl_down(part, off, 64);

    const int wid = tid >> 6;
    if (lane == 0) wsum[wid] = part;
    __syncthreads();
    if (tid == 0) {
        float tot = wsum[0] + wsum[1] + wsum[2] + wsum[3];
        atomicAdd(out, tot * scale);
    }
}

extern "C" void kernel_launch(void* const* d_in, const int* in_sizes, int n_in,
                              void* d_out, int out_size, void* d_ws, size_t ws_size,
                              hipStream_t stream)
{
    (void)n_in; (void)out_size; (void)d_ws; (void)ws_size;

    const float* pred = (const float*)d_in[0];
    const float* tru  = (const float*)d_in[1];
    float* out = (float*)d_out;

    const int B = in_sizes[0] / N_ELEM;   // 4096 rows

    hipMemsetAsync(out, 0, sizeof(float), stream);

    const float scale = 1.0f / ((float)N_ELEM * (float)B);
    w1_rows_kernel<<<B / 2, THREADS, 0, stream>>>(pred, tru, out, scale);
}

// Round 13
// 220.552 us; speedup vs baseline: 1.1807x; 1.0920x over previous
//
#include <hip/hip_runtime.h>

// WassersteinLoss: per-row W1 = (1/N) * sum_i |sort(u)[i] - sort(v)[i]|, mean over rows.
// R17: one-array-per-thread -> 8 waves/SIMD (2x occupancy).
//   R16 post-mortem: barrier merge ~1us; 6th structural attack flat. Hand-count
//   of VALU stream = 54us/SIMD floor vs conserved dur*VALUBusy ~115us -> either
//   counter includes stall cycles or per-SIMD issue ~45% (latency-bound at
//   4 waves/SIMD). Occupancy >16 waves/CU was NEVER cleanly tested (R6/R7 spill
//   masked it). Binding constraint: 64-float ru/rv array. Fix: split u/v across
//   WAVES, not registers. 512-thread block = 2 rows x 2 arrays x 128 threads;
//   each thread sorts ONE array (r[32]+t[16] ~ 54 VGPR, fits 64-cap of
//   launch_bounds(512,8)). Sort = mechanical single-array version of verified
//   R16 passes (same order -> bit-identical). Pairing: u-threads park sorted
//   rows in xbuf (stride 33), v-threads diff+reduce; reduction order exactly
//   preserved (u-wave zeros fold away; same per-t partials, same shfl tree).
//   LDS 33.8KB x 4 blocks/CU = 135KB <= 160 -> 32 waves/CU.
//   Pred: occupancy 38->65-75%, dur 147 -> 115-130us if latency-bound; ~147
//   null if issue-bound; WRITE_SIZE >> 64KB = spill -> revert to (512,6).
// Carried: blocked layout, ascending mirror bitonic, 2-VALU ce2, DPP m=1,2,8 +
//   mirrors X=1,3,7,15, pipelined bperm m=4,16,32 + mirrors X=31,63,
//   wave-role-split LDS t^127 stage, stride-33 (0 conflicts).

constexpr int N_ELEM  = 4096;
constexpr int V       = 32;     // elements per thread (one array)
constexpr int THREADS = 512;    // 8 waves = 2 rows x 2 arrays x 128 threads

// ---- compare-select: keep min(x,o) if keep_min, else max(x,o). ----
__device__ __forceinline__ float ce2(float x, float o, bool keep_min) {
    return ((o < x) != keep_min) ? x : o;
}

// ---- in-register ascending merge of S-blocks: mirror + descend S/4..1 ----
template<int S>
__device__ __forceinline__ void reg_merge(float r[V]) {
    #pragma unroll
    for (int k = 0; k < V; ++k) {
        if ((k & (S >> 1)) == 0) {
            const int j = k ^ (S - 1);          // complement low bits = mirror partner
            const float a = r[k], b = r[j];
            r[k] = fminf(a, b);
            r[j] = fmaxf(a, b);
        }
    }
    #pragma unroll
    for (int s = S >> 2; s >= 1; s >>= 1) {
        #pragma unroll
        for (int k = 0; k < V; ++k) {
            if ((k & s) == 0) {
                const float a = r[k], b = r[k + s];
                r[k]     = fminf(a, b);
                r[k + s] = fmaxf(a, b);
            }
        }
    }
}

// ---- ascending register descend, strides 16..1 (tail of every cross stage) ----
__device__ __forceinline__ void reg_tail_asc(float r[V]) {
    #pragma unroll
    for (int s = 16; s >= 1; s >>= 1) {
        #pragma unroll
        for (int k = 0; k < V; ++k) {
            if ((k & s) == 0) {
                const float a = r[k], b = r[k + s];
                r[k]     = fminf(a, b);
                r[k + s] = fmaxf(a, b);
            }
        }
    }
}

template<int CTRL>
__device__ __forceinline__ float dpp_x(float x) {
    return __int_as_float(__builtin_amdgcn_mov_dpp(__float_as_int(x), CTRL, 0xF, 0xF, true));
}
__device__ __forceinline__ float bperm_x(int pa, float x) {
    return __int_as_float(__builtin_amdgcn_ds_bpermute(pa, __float_as_int(x)));
}

// ---- descend xor pass (single array), partner lane^M, keep_min at (lane&M)==0.
//      bperm path: 16-elem issue/consume pipeline (16 DS in flight). ----
template<int M>
__device__ __forceinline__ void xor_pass1(float r[V], int lane) {
    const bool keep_min = (lane & M) == 0;
    if constexpr (M == 1 || M == 2 || M == 8) {
        constexpr int ctrl = (M == 1) ? 0xB1 : (M == 2) ? 0x4E : 0x128;
        #pragma unroll
        for (int k = 0; k < V; ++k)
            r[k] = ce2(r[k], dpp_x<ctrl>(r[k]), keep_min);
    } else {
        const int pa = (lane ^ M) << 2;
        float tt[16];
        #pragma unroll
        for (int k = 0; k < 16; ++k) tt[k] = bperm_x(pa, r[k]);        // issue c0
        #pragma unroll
        for (int k = 0; k < 16; ++k) {
            r[k] = ce2(r[k], tt[k], keep_min);                          // consume c0
            tt[k] = bperm_x(pa, r[16 + k]);                             // issue c1
        }
        #pragma unroll
        for (int k = 0; k < 16; ++k)
            r[16 + k] = ce2(r[16 + k], tt[k], keep_min);                // consume c1
    }
}

// ---- cross descend m=MMAX..1 then register tail (strides 16..1) ----
template<int MMAX>
__device__ __forceinline__ void cross_descend1(float r[V], int lane) {
    if constexpr (MMAX >= 32) xor_pass1<32>(r, lane);
    if constexpr (MMAX >= 16) xor_pass1<16>(r, lane);
    if constexpr (MMAX >= 8)  xor_pass1<8>(r, lane);
    if constexpr (MMAX >= 4)  xor_pass1<4>(r, lane);
    if constexpr (MMAX >= 2)  xor_pass1<2>(r, lane);
    if constexpr (MMAX >= 1)  xor_pass1<1>(r, lane);
    reg_tail_asc(r);
}

// DPP ctrl for mirror partner lane^X, or -1 (-> bperm).
template<int X>
static constexpr int mirror_dpp_ctrl() {
    return X == 1 ? 0xB1 : X == 3 ? 0x1B : X == 7 ? 0x141 : X == 15 ? 0x140 : -1;
}

// ---- cross mirror pass (single array): (t,k) <-> (t^X, 31-k);
//      keep_min at (lane & (X+1)/2)==0. Pairs (k,31-k) jointly (no hazard). ----
template<int X>
__device__ __forceinline__ void mirror_pass1(float r[V], int lane) {
    const bool keep_min = (lane & ((X + 1) >> 1)) == 0;
    constexpr int ctrl = mirror_dpp_ctrl<X>();
    if constexpr (ctrl != -1) {
        #pragma unroll
        for (int k = 0; k < V / 2; ++k) {
            const int j = V - 1 - k;
            const float a = dpp_x<ctrl>(r[j]);
            const float b = dpp_x<ctrl>(r[k]);
            r[k] = ce2(r[k], a, keep_min);
            r[j] = ce2(r[j], b, keep_min);
        }
    } else {
        const int pa = (lane ^ X) << 2;
        #pragma unroll
        for (int k = 0; k < V / 2; ++k) {
            const int j = V - 1 - k;
            const float a = bperm_x(pa, r[j]);
            const float b = bperm_x(pa, r[k]);
            r[k] = ce2(r[k], a, keep_min);
            r[j] = ce2(r[j], b, keep_min);
        }
    }
}

// ---- full merge stage S (64..2048): cross mirror + cross descend + reg tail ----
template<int S>
__device__ __forceinline__ void stage_m1(float r[V], int lane) {
    mirror_pass1<(S >> 5) - 1>(r, lane);   // X = S/32 - 1
    cross_descend1<(S >> 7)>(r, lane);     // m = S/128..1
}

__global__ __launch_bounds__(THREADS, 8) void w1_rows_kernel(
    const float* __restrict__ pred,
    const float* __restrict__ tru,
    float* __restrict__ out,
    float scale)
{
    // 4 groups (row x array) x 64 upper-slots x stride 33 = 8448 floats (33792 B).
    // Reused after a barrier as the u-park: 2 rows x 128 slots x stride 33.
    __shared__ float xbuf[8448];
    __shared__ float wsum[THREADS / 64];

    const int tid  = threadIdx.x;
    const int t    = tid & 127;            // thread index within (row, array)
    const int lane = tid & 63;
    const int grp  = tid >> 7;             // 0..3: row0-u, row0-v, row1-u, row1-v
    const int isv  = grp & 1;
    const int row  = blockIdx.x * 2 + (tid >> 8);
    const float* src = isv ? tru : pred;
    const size_t base = (size_t)row * N_ELEM + (size_t)t * V;

    // Blocked layout: thread t owns global indices [32t, 32t+32) of its array.
    float r[V];
    {
        const float4* s4 = (const float4*)(src + base);
        #pragma unroll
        for (int c = 0; c < V / 4; ++c) {
            float4 a = s4[c];
            r[4*c+0] = a.x; r[4*c+1] = a.y; r[4*c+2] = a.z; r[4*c+3] = a.w;
        }
    }

    // Stages S=2..32: fully in-register ascending sort of each 32-run.
    reg_merge<2>(r);
    reg_merge<4>(r);
    reg_merge<8>(r);
    reg_merge<16>(r);
    reg_merge<32>(r);

    // Stages S=64..2048: cross-lane mirror + descend, everything ascending.
    stage_m1<64>(r, lane);
    stage_m1<128>(r, lane);
    stage_m1<256>(r, lane);
    stage_m1<512>(r, lane);
    stage_m1<1024>(r, lane);
    stage_m1<2048>(r, lane);

    // Stage S=4096: mirror (t,k) <-> (t^127, 31-k) via LDS, per-group region.
    // Wave-role split: uppers (t&64) stage 32 regs; lowers read partner
    // reversed, keep min, write max back; uppers re-read. Wave-uniform.
    {
        const bool is_upper = (t & 64) != 0;
        const int  rb = grp * 2112;                  // 64 slots x 33
        const int  my = rb + lane * 33;              // uppers' own slot
        const int  pa = rb + (63 - lane) * 33;       // lowers' partner slot

        if (is_upper) {
            #pragma unroll
            for (int k = 0; k < V; ++k) xbuf[my + k] = r[k];
        }
        __syncthreads();
        if (!is_upper) {
            #pragma unroll
            for (int k = 0; k < V; ++k) {
                const int  e = V - 1 - k;
                const float o  = xbuf[pa + e];
                const float mx = fmaxf(r[k], o);
                r[k] = fminf(r[k], o);               // lower keeps min
                xbuf[pa + e] = mx;                   // partner's result
            }
        }
        __syncthreads();
        if (is_upper) {
            #pragma unroll
            for (int k = 0; k < V; ++k) r[k] = xbuf[my + k];
        }

        cross_descend1<32>(r, lane);                 // strides 1024..32 + reg tail
    }

    // Pair u/v through LDS: u-threads park sorted rows; v-threads diff+reduce.
    __syncthreads();                                 // all groups done with xbuf
    const int pb = (tid >> 8) * 4224 + t * 33;       // park slot (stride 33)
    if (!isv) {
        #pragma unroll
        for (int k = 0; k < V; ++k) xbuf[pb + k] = r[k];
    }
    __syncthreads();

    float part = 0.f;
    if (isv) {
        #pragma unroll
        for (int k = 0; k < V; ++k) part += fabsf(xbuf[pb + k] - r[k]);
    }

    #pragma unroll
    for (int off = 32; off > 0; off >>= 1)
        part += __shfl_down(part, off, 64);

    const int wid = tid >> 6;
    if (lane == 0) wsum[wid] = part;
    __syncthreads();
    if (tid == 0) {
        float tot = wsum[0];
        #pragma unroll
        for (int w = 1; w < THREADS / 64; ++w) tot += wsum[w];
        atomicAdd(out, tot * scale);
    }
}

extern "C" void kernel_launch(void* const* d_in, const int* in_sizes, int n_in,
                              void* d_out, int out_size, void* d_ws, size_t ws_size,
                              hipStream_t stream)
{
    (void)n_in; (void)out_size; (void)d_ws; (void)ws_size;

    const float* pred = (const float*)d_in[0];
    const float* tru  = (const float*)d_in[1];
    float* out = (float*)d_out;

    const int B = in_sizes[0] / N_ELEM;   // 4096 rows

    hipMemsetAsync(out, 0, sizeof(float), stream);

    const float scale = 1.0f / ((float)N_ELEM * (float)B);
    w1_rows_kernel<<<B / 2, THREADS, 0, stream>>>(pred, tru, out, scale);
}